// Round 14
// baseline (102.805 us; speedup 1.0000x reference)
//
#include <hip/hip_runtime.h>
#include <hip/hip_bf16.h>

// OnlineTripletLoss: B=8192, D=128, fp32 embeddings, int32 labels, scalar out.
// LABEL-SORTED barrier-free design: counting-sort rows by label (positions via
// atomics -- any within-label order is valid; mean/max/min are permutation-
// invariant and the fixed-point sum keeps d_out bit-deterministic). Waves then
// see (mostly) single-label row tiles + contiguous positive col ranges, so the
// per-pair epilogue collapses from ~7 VALU (bfe+cmp+selects) to 2 (fmaf+min or
// fmaf+max) on scalar-classified pure groups. Gram core = r12 chassis: 4096
// independent waves, wave-private LDS dbuf via global_load_lds, counted
// vmcnt(4), zero barriers; r9/r11 &15 swizzle (measured 0 conflicts).

#define BB 8192
#define DD 128
#define MARGIN 0.2f
#define EPS 1e-12f

#define GCOLS 16
#define COLS_PER_WAVE 512
#define NGROUPS (COLS_PER_WAVE / GCOLS)        // 32

typedef __attribute__((ext_vector_type(8))) short short8;
typedef __attribute__((ext_vector_type(4))) float f32x4;

__device__ inline unsigned short f2bf(float f) {
    __hip_bfloat16 h = __float2bfloat16(f);
    unsigned short u;
    __builtin_memcpy(&u, &h, 2);
    return u;
}

// ---- K0: zero the small state (ws is poisoned 0xAA) ------------------------
__global__ __launch_bounds__(256) void init_small(
    unsigned* __restrict__ hist, unsigned* __restrict__ cnt,
    unsigned long long* __restrict__ fsum, unsigned* __restrict__ fdone) {
    const int t = threadIdx.x;
    if (t < 64) { hist[t] = 0u; cnt[t] = 0u; }
    if (t == 0) { *fsum = 0ull; *fdone = 0u; }
}

// ---- K1: row sq-norms + {sq,label} meta + label histogram + hp/mn init -----
__global__ __launch_bounds__(256) void prep_meta(
    const float* __restrict__ x, const int* __restrict__ lab,
    float2* __restrict__ meta, unsigned* __restrict__ hist,
    unsigned* __restrict__ hp2, unsigned* __restrict__ mn2) {
    const int t = blockIdx.x * 256 + threadIdx.x;   // 0 .. 8192*32-1
    const int row = t >> 5;                          // 32 threads per row
    const float4 v = reinterpret_cast<const float4*>(x)[t];
    float s = v.x * v.x + v.y * v.y + v.z * v.z + v.w * v.w;
    #pragma unroll
    for (int m = 16; m >= 1; m >>= 1) s += __shfl_xor(s, m, 64);
    if ((t & 31) == 0) {
        const int l = lab[row];
        meta[row] = make_float2(s, __int_as_float(l));
        atomicAdd(&hist[l], 1u);
    }
    if (t < BB) { hp2[t] = 0u; mn2[t] = 0x7f800000u; }  // 0, +inf
}

// ---- K2: exclusive scan of the 64-bin histogram (one wave) -----------------
__global__ __launch_bounds__(64) void scan64(
    const unsigned* __restrict__ hist, int* __restrict__ labstart) {
    const int l = threadIdx.x;                  // 0..63
    unsigned v = hist[l];
    #pragma unroll
    for (int off = 1; off < 64; off <<= 1) {
        const unsigned n = __shfl_up(v, off, 64);
        if (l >= off) v += n;
    }
    labstart[l + 1] = (int)v;                   // inclusive -> start of l+1
    if (l == 0) labstart[0] = 0;
}

// ---- K3: scatter rows to sorted positions ----------------------------------
__global__ __launch_bounds__(256) void scatter_idx(
    const float2* __restrict__ meta, const int* __restrict__ labstart,
    unsigned* __restrict__ cnt, int* __restrict__ prow,
    float2* __restrict__ meta_s) {
    const int r = blockIdx.x * 256 + threadIdx.x;   // 32 blocks -> 8192 rows
    const float2 m = meta[r];
    const int l = __float_as_int(m.y);
    const int p = labstart[l] + (int)atomicAdd(&cnt[l], 1u);
    prow[r] = p;
    meta_s[p] = m;
}

// ---- K4: fp32 -> bf16 copy into sorted order -------------------------------
__global__ __launch_bounds__(256) void copy_sorted(
    const float* __restrict__ x, const int* __restrict__ prow,
    unsigned short* __restrict__ xs) {
    const int t = blockIdx.x * 256 + threadIdx.x;   // 0 .. 8192*32-1
    const int row = t >> 5;
    const int p = prow[row];
    const float4 v = reinterpret_cast<const float4*>(x)[t];
    union { unsigned short u[4]; uint2 w; } pk;
    pk.u[0] = f2bf(v.x); pk.u[1] = f2bf(v.y);
    pk.u[2] = f2bf(v.z); pk.u[3] = f2bf(v.w);
    reinterpret_cast<uint2*>(xs)[p * 32 + (t & 31)] = pk.w;
}

// ---- K5: main --------------------------------------------------------------
// 1024 blocks x 256 thr = 4096 independent waves (32 sorted rows x 512 sorted
// cols each), zero barriers. Per 16-col group: 4KB B staged to wave-private
// LDS dbuf (4 gload_lds, vmcnt(4) counted), ds_read b128 swizzled, 8 MFMA,
// then a scalar-classified epilogue:
//   uni-label wave + group outside [ps,pe)  -> pure NEG: fmaf+min only
//   uni-label wave + group inside  [ps,pe)  -> pure POS: fmaf+max only
//   uni-label wave + straddling             -> uniform-label compare selects
//   mixed-label wave (<=25% of waves)       -> r12 per-slot byte-compare path
__global__ __launch_bounds__(256) void triplet_main(
    const unsigned short* __restrict__ xs, const float2* __restrict__ meta_s,
    const int* __restrict__ labstart, unsigned* __restrict__ hp2,
    unsigned* __restrict__ mn2) {
    const int tid  = threadIdx.x;
    const int wave = tid >> 6;
    const int lane = tid & 63;
    const int l15  = lane & 15;
    const int lhi  = lane >> 4;

    const int cc    = blockIdx.x & 15;               // col chunk
    const int rw    = (blockIdx.x >> 4) * 4 + wave;  // row-wave 0..255
    const int rbase = rw * 32;
    const int cbase = cc * COLS_PER_WAVE;

    __shared__ unsigned short sbuf[4][2][GCOLS * DD];  // 4 waves x 2 x 4 KB
    __shared__ float2 smeta[COLS_PER_WAVE];            // 4 KB, benign-race dup

    // A fragments: two 16-row tiles (sorted rows), K=128 in 4 slices.
    short8 a0[4], a1[4];
    {
        const unsigned short* ar0 = xs + (size_t)(rbase + l15) * DD + lhi * 8;
        const unsigned short* ar1 = ar0 + 16 * DD;
        #pragma unroll
        for (int s = 0; s < 4; ++s) {
            a0[s] = *reinterpret_cast<const short8*>(ar0 + s * 32);
            a1[s] = *reinterpret_cast<const short8*>(ar1 + s * 32);
        }
    }
    // Wave-uniform label window (sorted rows).
    const int L0  = __builtin_amdgcn_readfirstlane(__float_as_int(meta_s[rbase].y));
    const int L31 = __builtin_amdgcn_readfirstlane(__float_as_int(meta_s[rbase + 31].y));
    const int ps  = labstart[L0];
    const int pe  = labstart[L0 + 1];
    const bool uni = (L0 == L31);

    // Per-slot labels for the mixed-wave fallback (C/D: row_local = lhi*4+k).
    unsigned li0 = 0, li1 = 0;
    #pragma unroll
    for (int k = 0; k < 4; ++k) {
        li0 |= ((unsigned)__float_as_int(meta_s[rbase + lhi * 4 + k].y) & 255u) << (8 * k);
        li1 |= ((unsigned)__float_as_int(meta_s[rbase + 16 + lhi * 4 + k].y) & 255u) << (8 * k);
    }
    float hp0[4], mn0[4], hp1[4], mn1[4];
    #pragma unroll
    for (int k = 0; k < 4; ++k) {
        hp0[k] = -__builtin_inff(); mn0[k] = __builtin_inff();
        hp1[k] = -__builtin_inff(); mn1[k] = __builtin_inff();
    }

    // Stage one 16-col group (4KB) into this wave's buf[g&1]. LDS dest linear;
    // global SOURCE pre-swizzled: LDS(col,b) = G(col, b ^ ((col&15)<<4)).
    auto stage = [&](int g) {
        const char* sb_ = (const char*)(xs + (size_t)(cbase + g * GCOLS) * DD);
        char* db = (char*)&sbuf[wave][g & 1][0];
        #pragma unroll
        for (int p = 0; p < 4; ++p) {
            const int o     = p * 1024 + lane * 16;
            const int col   = o >> 8;
            const int inner = (o & 255) ^ ((col & 15) << 4);
            __builtin_amdgcn_global_load_lds(
                (const __attribute__((address_space(1))) void*)(sb_ + col * 256 + inner),
                (__attribute__((address_space(3))) void*)(db + p * 1024), 16, 0, 0);
        }
    };

    auto body = [&](int g, bool do_stage) {
        const char* bb_ = (const char*)&sbuf[wave][g & 1][0];
        short8 b[4];
        #pragma unroll
        for (int s = 0; s < 4; ++s)
            b[s] = *reinterpret_cast<const short8*>(
                bb_ + l15 * 256 + ((s * 64 + lhi * 16) ^ (l15 << 4)));
        const float2 cm = smeta[g * GCOLS + l15];
        asm volatile("s_waitcnt lgkmcnt(0)" ::: "memory");
        __builtin_amdgcn_sched_barrier(0);          // rule 18: fence before MFMA
        if (do_stage) stage(g + 2);
        f32x4 acc0 = {}, acc1 = {};
        #pragma unroll
        for (int s = 0; s < 4; ++s) {
            acc0 = __builtin_amdgcn_mfma_f32_16x16x32_bf16(a0[s], b[s], acc0, 0, 0, 0);
            acc1 = __builtin_amdgcn_mfma_f32_16x16x32_bf16(a1[s], b[s], acc1, 0, 0, 0);
        }
        const float sqj = cm.x;
        const int c0 = cbase + g * GCOLS;
        if (uni) {
            if (c0 >= pe || c0 + GCOLS <= ps) {
                // pure negative: 2 VALU/element
                #pragma unroll
                for (int k = 0; k < 4; ++k) {
                    mn0[k] = fminf(mn0[k], fmaf(acc0[k], -2.0f, sqj));
                    mn1[k] = fminf(mn1[k], fmaf(acc1[k], -2.0f, sqj));
                }
            } else if (c0 >= ps && c0 + GCOLS <= pe) {
                // pure positive (self-pair folds in: d2'~-sqi -> ~0, never wins)
                #pragma unroll
                for (int k = 0; k < 4; ++k) {
                    hp0[k] = fmaxf(hp0[k], fmaf(acc0[k], -2.0f, sqj));
                    hp1[k] = fmaxf(hp1[k], fmaf(acc1[k], -2.0f, sqj));
                }
            } else {
                // boundary group: uniform-label compare per col
                const bool eq = (__float_as_int(cm.y) == L0);
                #pragma unroll
                for (int k = 0; k < 4; ++k) {
                    const float d0 = fmaf(acc0[k], -2.0f, sqj);
                    const float d1 = fmaf(acc1[k], -2.0f, sqj);
                    hp0[k] = fmaxf(hp0[k], eq ? d0 : -__builtin_inff());
                    mn0[k] = fminf(mn0[k], eq ? __builtin_inff() : d0);
                    hp1[k] = fmaxf(hp1[k], eq ? d1 : -__builtin_inff());
                    mn1[k] = fminf(mn1[k], eq ? __builtin_inff() : d1);
                }
            }
        } else {
            // mixed-label wave: per-slot byte compares (r12 path)
            const int labj = __float_as_int(cm.y) & 255;
            #pragma unroll
            for (int k = 0; k < 4; ++k) {
                const float d0 = fmaf(acc0[k], -2.0f, sqj);
                const float d1 = fmaf(acc1[k], -2.0f, sqj);
                const bool e0k = (int)((li0 >> (8 * k)) & 255u) == labj;
                const bool e1k = (int)((li1 >> (8 * k)) & 255u) == labj;
                hp0[k] = fmaxf(hp0[k], e0k ? d0 : -__builtin_inff());
                mn0[k] = fminf(mn0[k], e0k ? __builtin_inff() : d0);
                hp1[k] = fmaxf(hp1[k], e1k ? d1 : -__builtin_inff());
                mn1[k] = fminf(mn1[k], e1k ? __builtin_inff() : d1);
            }
        }
    };

    // Prologue: smeta (4 dup gload_lds per wave, identical bytes, race-benign),
    // then groups 0,1. Counted-vmcnt invariant as r12: vmcnt(4) at each top.
    {
        const char* msrc = (const char*)(meta_s + cbase);
        #pragma unroll
        for (int p = 0; p < 4; ++p)
            __builtin_amdgcn_global_load_lds(
                (const __attribute__((address_space(1))) void*)(msrc + p * 1024 + lane * 16),
                (__attribute__((address_space(3))) void*)((char*)smeta + p * 1024), 16, 0, 0);
    }
    stage(0);
    stage(1);
    for (int g = 0; g < NGROUPS - 2; ++g) {
        asm volatile("s_waitcnt vmcnt(4)" ::: "memory");
        body(g, true);
    }
    asm volatile("s_waitcnt vmcnt(4)" ::: "memory");
    body(NGROUPS - 2, false);
    asm volatile("s_waitcnt vmcnt(0)" ::: "memory");
    body(NGROUPS - 1, false);

    // Epilogue: add deferred sqi; clamp hp >= 0; 16-lane reduce; atomics.
    #pragma unroll
    for (int k = 0; k < 4; ++k) {
        const float sqi0 = meta_s[rbase + lhi * 4 + k].x;
        const float sqi1 = meta_s[rbase + 16 + lhi * 4 + k].x;
        hp0[k] = fmaxf(sqi0 + hp0[k], 0.0f);  mn0[k] = sqi0 + mn0[k];
        hp1[k] = fmaxf(sqi1 + hp1[k], 0.0f);  mn1[k] = sqi1 + mn1[k];
    }
    #pragma unroll
    for (int m = 1; m < 16; m <<= 1) {
        #pragma unroll
        for (int k = 0; k < 4; ++k) {
            hp0[k] = fmaxf(hp0[k], __shfl_xor(hp0[k], m, 64));
            mn0[k] = fminf(mn0[k], __shfl_xor(mn0[k], m, 64));
            hp1[k] = fmaxf(hp1[k], __shfl_xor(hp1[k], m, 64));
            mn1[k] = fminf(mn1[k], __shfl_xor(mn1[k], m, 64));
        }
    }
    if (l15 == 0) {
        #pragma unroll
        for (int k = 0; k < 4; ++k) {
            const int i0 = rbase + lhi * 4 + k;      // sorted index (valid:
            const int i1 = i0 + 16;                  // mean is perm-invariant)
            atomicMax(&hp2[i0], __float_as_uint(hp0[k]));
            atomicMin(&mn2[i0], __float_as_uint(mn0[k]));
            atomicMax(&hp2[i1], __float_as_uint(hp1[k]));
            atomicMin(&mn2[i1], __float_as_uint(mn1[k]));
        }
    }
}

// ---- K6: finalize -----------------------------------------------------------
__device__ inline float d_of(float d2) {
    return (d2 > EPS) ? sqrtf(d2) : 0.0f;
}

__global__ __launch_bounds__(1024) void finalize_kernel(
    const unsigned* __restrict__ hp2, const unsigned* __restrict__ mn2,
    unsigned long long* __restrict__ fsum, unsigned* __restrict__ fdone,
    float* __restrict__ out) {
    const int i = blockIdx.x * 1024 + threadIdx.x;
    const float hpv = d_of(__uint_as_float(hp2[i]));
    const float mnv = d_of(__uint_as_float(mn2[i]));
    float acc = fmaxf(hpv - mnv + MARGIN, 0.0f);

    #pragma unroll
    for (int m = 1; m < 64; m <<= 1) acc += __shfl_xor(acc, m, 64);
    __shared__ float ws[16];
    const int wave = threadIdx.x >> 6;
    if ((threadIdx.x & 63) == 0) ws[wave] = acc;
    __syncthreads();
    if (threadIdx.x == 0) {
        float s = 0.0f;
        #pragma unroll
        for (int w = 0; w < 16; ++w) s += ws[w];
        atomicAdd(fsum, (unsigned long long)((double)s * 4294967296.0));
        __threadfence();
        const unsigned old = atomicAdd(fdone, 1u);
        if (old == gridDim.x - 1) {
            const unsigned long long total = atomicAdd(fsum, 0ull);
            out[0] = (float)((double)total / 4294967296.0 / (double)BB);
        }
    }
}

extern "C" void kernel_launch(void* const* d_in, const int* in_sizes, int n_in,
                              void* d_out, int out_size, void* d_ws, size_t ws_size,
                              hipStream_t stream) {
    const float* x = (const float*)d_in[0];
    const int* lab = (const int*)d_in[1];
    float* out = (float*)d_out;

    char* ws = (char*)d_ws;
    unsigned short* xs = (unsigned short*)ws;                        // 2 MB sorted bf16
    size_t off = (size_t)BB * DD * 2;
    float2* meta   = (float2*)(ws + off);  off += (size_t)BB * 8;    // 64 KB
    float2* meta_s = (float2*)(ws + off);  off += (size_t)BB * 8;    // 64 KB
    unsigned* hp2  = (unsigned*)(ws + off); off += (size_t)BB * 4;   // 32 KB
    unsigned* mn2  = (unsigned*)(ws + off); off += (size_t)BB * 4;   // 32 KB
    int* prow      = (int*)(ws + off);      off += (size_t)BB * 4;   // 32 KB
    unsigned* hist = (unsigned*)(ws + off); off += 64 * 4;
    unsigned* cnt  = (unsigned*)(ws + off); off += 64 * 4;
    int* labstart  = (int*)(ws + off);      off += 65 * 4;
    unsigned long long* fsum = (unsigned long long*)(ws + ((off + 7) & ~(size_t)7));
    unsigned* fdone = (unsigned*)((char*)fsum + 8);

    init_small<<<1, 256, 0, stream>>>(hist, cnt, fsum, fdone);
    prep_meta<<<(BB * 32) / 256, 256, 0, stream>>>(x, lab, meta, hist, hp2, mn2);
    scan64<<<1, 64, 0, stream>>>(hist, labstart);
    scatter_idx<<<BB / 256, 256, 0, stream>>>(meta, labstart, cnt, prow, meta_s);
    copy_sorted<<<(BB * 32) / 256, 256, 0, stream>>>(x, prow, xs);
    triplet_main<<<1024, 256, 0, stream>>>(xs, meta_s, labstart, hp2, mn2);
    finalize_kernel<<<BB / 1024, 1024, 0, stream>>>(hp2, mn2, fsum, fdone, out);
}

// Round 15
// 43.148 us; speedup vs baseline: 2.3826x; 2.3826x over previous
//
#include <hip/hip_runtime.h>
#include <hip/hip_bf16.h>

// OnlineTripletLoss: B=8192, D=128, fp32 embeddings, int32 labels, scalar out.
// r10 chassis (best: 32 waves/CU by construction, shared 32-col LDS stages,
// 3-buffer ring, raw s_barrier + counted lgkmcnt(0)/vmcnt(1)) widened to 32
// rows/wave via TWO 16x16 A-tiles sharing each B-fragment (r12-proven 56-VGPR
// layout): halves LDS reads, staging bytes, and barrier count per output.
// Grid (32,32): 1024 blocks x 8 waves = 8192 waves = 32 waves/CU (cap).
// Row&15 source-pre-swizzle (0 conflicts measured r9/r11); sqi-deferred
// epilogue; packed labels; deterministic fixed-point finalize.

#define BB 8192
#define DD 128
#define MARGIN 0.2f
#define EPS 1e-12f

#define COLS_PER_BLOCK 256
#define ROWS_PER_BLOCK 256                     // 8 waves x 32 rows
#define STAGE_COLS 32
#define NSTAGES 8                              // COLS_PER_BLOCK / STAGE_COLS
#define STAGE_SHORTS (STAGE_COLS * DD)         // 4096 shorts = 8 KB

typedef __attribute__((ext_vector_type(8))) short short8;
typedef __attribute__((ext_vector_type(4))) float f32x4;

__device__ inline unsigned short f2bf(float f) {
    __hip_bfloat16 h = __float2bfloat16(f);
    unsigned short u;
    __builtin_memcpy(&u, &h, 2);
    return u;
}

// ---- prep: bf16 copy + packed {sq,label} meta + init reduction state -------
__global__ __launch_bounds__(256) void prep_kernel(
    const float* __restrict__ x, const int* __restrict__ lab,
    unsigned short* __restrict__ xb, float2* __restrict__ meta,
    unsigned* __restrict__ hp2, unsigned* __restrict__ mn2,
    unsigned long long* __restrict__ fsum, unsigned* __restrict__ fdone) {
    int t = blockIdx.x * blockDim.x + threadIdx.x;   // 0 .. 8192*32-1
    int row = t >> 5;                                 // 32 threads per row
    const float4 v = reinterpret_cast<const float4*>(x)[t];

    union { unsigned short u[4]; uint2 w; } p;
    p.u[0] = f2bf(v.x); p.u[1] = f2bf(v.y);
    p.u[2] = f2bf(v.z); p.u[3] = f2bf(v.w);
    reinterpret_cast<uint2*>(xb)[t] = p.w;

    float s = v.x * v.x + v.y * v.y + v.z * v.z + v.w * v.w;
    #pragma unroll
    for (int m = 16; m >= 1; m >>= 1) s += __shfl_xor(s, m, 64);  // within 32-lane row group
    if ((t & 31) == 0) meta[row] = make_float2(s, __int_as_float(lab[row]));

    if (t < BB) { hp2[t] = 0u; mn2[t] = 0x7f800000u; }  // 0, +inf
    if (t == 0) { *fsum = 0ull; *fdone = 0u; }
}

// ---- main ------------------------------------------------------------------
// grid (32, 32), 512 threads = 8 waves x 32 rows = 256 rows x 256-col chunk.
// Per stage (32 cols, 8 KB): 1 gload_lds per thread; 3-buffer ring; raw
// barrier + counted vmcnt(1) keeps next stage's loads in flight. Each wave
// reads B-fragments once and feeds TWO 16-row A-tiles (8 MFMA per group).
__global__ __launch_bounds__(512) void triplet_main(
    const unsigned short* __restrict__ xb, const float2* __restrict__ meta,
    unsigned* __restrict__ hp2, unsigned* __restrict__ mn2) {
    const int tid  = threadIdx.x;
    const int wave = tid >> 6;
    const int lane = tid & 63;
    const int l15  = lane & 15;
    const int lhi  = lane >> 4;
    const int rbase = blockIdx.x * ROWS_PER_BLOCK + wave * 32;
    const int cbase = blockIdx.y * COLS_PER_BLOCK;

    __shared__ unsigned short sb[3][STAGE_SHORTS];   // 3 x 8 KB
    __shared__ float2 smeta[COLS_PER_BLOCK];         // 2 KB

    // A fragments: two 16-row tiles, K=128 in 4 slices (held whole kernel).
    // mfma_f32_16x16x32_bf16 A layout: row = lane&15, k = (lane>>4)*8 + i.
    short8 a0[4], a1[4];
    {
        const unsigned short* ar0 = xb + (size_t)(rbase + l15) * DD + lhi * 8;
        const unsigned short* ar1 = ar0 + 16 * DD;
        #pragma unroll
        for (int s = 0; s < 4; ++s) {
            a0[s] = *reinterpret_cast<const short8*>(ar0 + s * 32);
            a1[s] = *reinterpret_cast<const short8*>(ar1 + s * 32);
        }
    }
    // Slot labels (C/D: col = lane&15, row_local = lhi*4 + k), packed bytes.
    unsigned li0 = 0, li1 = 0;
    #pragma unroll
    for (int k = 0; k < 4; ++k) {
        li0 |= ((unsigned)__float_as_int(meta[rbase + lhi * 4 + k].y) & 255u) << (8 * k);
        li1 |= ((unsigned)__float_as_int(meta[rbase + 16 + lhi * 4 + k].y) & 255u) << (8 * k);
    }
    float hp0[4], mn0[4], hp1[4], mn1[4];
    #pragma unroll
    for (int k = 0; k < 4; ++k) {
        hp0[k] = -__builtin_inff(); mn0[k] = __builtin_inff();
        hp1[k] = -__builtin_inff(); mn1[k] = __builtin_inff();
    }

    // Stage 32 cols (8 KB): 1 x 16B gload_lds per thread. LDS dest linear
    // (wave-uniform base + lane*16); global SOURCE pre-swizzled:
    // LDS(col, b) = G(col, b ^ ((col&15)<<4)).
    auto stage = [&](int g, int buf) {
        const char* src_base = (const char*)(xb + (size_t)(cbase + g * STAGE_COLS) * DD);
        const int o   = tid * 16;                       // 0..8191
        const int row = o >> 8;                         // col index 0..31
        const int byt = (o & 255) ^ ((row & 15) << 4);
        const char* src = src_base + row * 256 + byt;
        char* dst = (char*)&sb[buf][0] + wave * 1024;
        __builtin_amdgcn_global_load_lds(
            (const __attribute__((address_space(1))) void*)src,
            (__attribute__((address_space(3))) void*)dst, 16, 0, 0);
    };

    auto compute_group = [&](int st, int gg, const char* base) {
        const int jl = gg * 16 + l15;                   // col within stage (0..31)
        const int rowoff = jl * 256;
        const int swz = (jl & 15) << 4;
        short8 b[4];
        #pragma unroll
        for (int s = 0; s < 4; ++s)
            b[s] = *reinterpret_cast<const short8*>(
                base + rowoff + ((s * 64 + lhi * 16) ^ swz));
        f32x4 acc0 = {}, acc1 = {};
        #pragma unroll
        for (int s = 0; s < 4; ++s) {
            acc0 = __builtin_amdgcn_mfma_f32_16x16x32_bf16(a0[s], b[s], acc0, 0, 0, 0);
            acc1 = __builtin_amdgcn_mfma_f32_16x16x32_bf16(a1[s], b[s], acc1, 0, 0, 0);
        }
        const float2 mj = smeta[st * STAGE_COLS + jl];
        const float sqj = mj.x;
        const int   labj = __float_as_int(mj.y) & 255;
        #pragma unroll
        for (int k = 0; k < 4; ++k) {
            const float d0 = fmaf(acc0[k], -2.0f, sqj);  // sqj - 2 dot (sqi deferred)
            const float d1 = fmaf(acc1[k], -2.0f, sqj);
            const bool e0 = (int)((li0 >> (8 * k)) & 255u) == labj;
            const bool e1 = (int)((li1 >> (8 * k)) & 255u) == labj;
            // self-pair folds into hp: d2' ~ -sqi -> ~0 after +sqi, never wins.
            hp0[k] = fmaxf(hp0[k], e0 ? d0 : -__builtin_inff());
            mn0[k] = fminf(mn0[k], e0 ? __builtin_inff() : d0);
            hp1[k] = fmaxf(hp1[k], e1 ? d1 : -__builtin_inff());
            mn1[k] = fminf(mn1[k], e1 ? __builtin_inff() : d1);
        }
    };

    // Prologue: smeta (2 dup gload_lds per wave -- identical bytes, benign
    // race, keeps per-wave vmcnt counts uniform), then stages 0,1.
    {
        const char* msrc = (const char*)(meta + cbase);
        #pragma unroll
        for (int p = 0; p < 2; ++p)
            __builtin_amdgcn_global_load_lds(
                (const __attribute__((address_space(1))) void*)(msrc + p * 1024 + lane * 16),
                (__attribute__((address_space(3))) void*)((char*)smeta + p * 1024), 16, 0, 0);
    }
    stage(0, 0);
    stage(1, 1);

    // 3-buffer pipeline: at iter st, outstanding (FIFO) = [stage st, stage
    // st+1] (+2 smeta at st=0, drained by the same wait). vmcnt(1) -> stage st
    // landed, st+1 in flight across the RAW barrier; lgkmcnt(0) -> this wave's
    // reads of the buffer stage st+2 will overwrite are done.
    #pragma unroll
    for (int st = 0; st < NSTAGES; ++st) {
        if (st < NSTAGES - 1)
            asm volatile("s_waitcnt lgkmcnt(0) vmcnt(1)" ::: "memory");
        else
            asm volatile("s_waitcnt lgkmcnt(0) vmcnt(0)" ::: "memory");
        __builtin_amdgcn_s_barrier();
        __builtin_amdgcn_sched_barrier(0);
        if (st + 2 < NSTAGES) stage(st + 2, (st + 2) % 3);
        const char* base = (const char*)&sb[st % 3][0];
        compute_group(st, 0, base);
        __builtin_amdgcn_sched_barrier(0);   // keep live sets (and VGPRs) small
        compute_group(st, 1, base);
    }

    // Epilogue: add deferred sqi; clamp hp >= 0 (exact: ref max(d*posmask)>=0);
    // reduce across the 16 col-lanes; one atomic pair per row.
    #pragma unroll
    for (int k = 0; k < 4; ++k) {
        const float sqi0 = meta[rbase + lhi * 4 + k].x;
        const float sqi1 = meta[rbase + 16 + lhi * 4 + k].x;
        hp0[k] = fmaxf(sqi0 + hp0[k], 0.0f);  mn0[k] = sqi0 + mn0[k];
        hp1[k] = fmaxf(sqi1 + hp1[k], 0.0f);  mn1[k] = sqi1 + mn1[k];
    }
    #pragma unroll
    for (int m = 1; m < 16; m <<= 1) {
        #pragma unroll
        for (int k = 0; k < 4; ++k) {
            hp0[k] = fmaxf(hp0[k], __shfl_xor(hp0[k], m, 64));
            mn0[k] = fminf(mn0[k], __shfl_xor(mn0[k], m, 64));
            hp1[k] = fmaxf(hp1[k], __shfl_xor(hp1[k], m, 64));
            mn1[k] = fminf(mn1[k], __shfl_xor(mn1[k], m, 64));
        }
    }
    if (l15 == 0) {   // lanes 0,16,32,48 hold the four lhi row-groups
        #pragma unroll
        for (int k = 0; k < 4; ++k) {
            const int i0 = rbase + lhi * 4 + k;
            const int i1 = i0 + 16;
            atomicMax(&hp2[i0], __float_as_uint(hp0[k]));  // >=0: uint order == float order
            atomicMin(&mn2[i0], __float_as_uint(mn0[k]));  // >=0 or +inf
            atomicMax(&hp2[i1], __float_as_uint(hp1[k]));
            atomicMin(&mn2[i1], __float_as_uint(mn1[k]));
        }
    }
}

// ---- finalize: per-row loss + deterministic fixed-point mean ---------------
// hardest_negative = min_neq d (every row has negatives: 64 labels / 8192).
__device__ inline float d_of(float d2) {
    return (d2 > EPS) ? sqrtf(d2) : 0.0f;
}

__global__ __launch_bounds__(1024) void finalize_kernel(
    const unsigned* __restrict__ hp2, const unsigned* __restrict__ mn2,
    unsigned long long* __restrict__ fsum, unsigned* __restrict__ fdone,
    float* __restrict__ out) {
    const int i = blockIdx.x * 1024 + threadIdx.x;   // 8 blocks x 1024 rows
    const float hpv = d_of(__uint_as_float(hp2[i]));
    const float mnv = d_of(__uint_as_float(mn2[i]));
    float acc = fmaxf(hpv - mnv + MARGIN, 0.0f);

    #pragma unroll
    for (int m = 1; m < 64; m <<= 1) acc += __shfl_xor(acc, m, 64);
    __shared__ float ws[16];
    const int wave = threadIdx.x >> 6;
    if ((threadIdx.x & 63) == 0) ws[wave] = acc;
    __syncthreads();
    if (threadIdx.x == 0) {
        float s = 0.0f;
        #pragma unroll
        for (int w = 0; w < 16; ++w) s += ws[w];
        // deterministic: integer atomic adds are order-independent
        atomicAdd(fsum, (unsigned long long)((double)s * 4294967296.0));
        __threadfence();
        const unsigned old = atomicAdd(fdone, 1u);
        if (old == gridDim.x - 1) {
            const unsigned long long total = atomicAdd(fsum, 0ull);
            out[0] = (float)((double)total / 4294967296.0 / (double)BB);
        }
    }
}

extern "C" void kernel_launch(void* const* d_in, const int* in_sizes, int n_in,
                              void* d_out, int out_size, void* d_ws, size_t ws_size,
                              hipStream_t stream) {
    const float* x = (const float*)d_in[0];
    const int* lab = (const int*)d_in[1];
    float* out = (float*)d_out;

    char* ws = (char*)d_ws;
    unsigned short* xb = (unsigned short*)ws;                          // 2 MB
    float2* meta = (float2*)(ws + (size_t)BB * DD * 2);                // 64 KB
    unsigned* hp2 = (unsigned*)(ws + (size_t)BB * DD * 2 + BB * 8);
    unsigned* mn2 = (unsigned*)(ws + (size_t)BB * DD * 2 + BB * 12);
    unsigned long long* fsum = (unsigned long long*)(ws + (size_t)BB * DD * 2 + BB * 16);
    unsigned* fdone = (unsigned*)(ws + (size_t)BB * DD * 2 + BB * 16 + 8);

    prep_kernel<<<(BB * DD / 4) / 256, 256, 0, stream>>>(x, lab, xb, meta, hp2, mn2, fsum, fdone);
    dim3 grid(BB / ROWS_PER_BLOCK, BB / COLS_PER_BLOCK);
    triplet_main<<<grid, 512, 0, stream>>>(xb, meta, hp2, mn2);
    finalize_kernel<<<BB / 1024, 1024, 0, stream>>>(hp2, mn2, fsum, fdone, out);
}

// Round 16
// 40.684 us; speedup vs baseline: 2.5269x; 1.0606x over previous
//
#include <hip/hip_runtime.h>
#include <hip/hip_bf16.h>

// OnlineTripletLoss: B=8192, D=128, fp32 embeddings, int32 labels, scalar out.
// r10 chassis (best measured: 16x16 single A-tile, 56 VGPR -> 32 waves/CU,
// shared 32-col LDS stages, raw s_barrier + counted waits) + two changes:
//   (1) 4-buffer ring with vmcnt(2): TWO stages in flight across each barrier
//   (2) bijective XCD swizzle: each XCD owns 2 column chunks -> L2-local B
// r15 lesson: 2-tile layouts need ~85 VGPR -> occupancy halves -> no win.
// Row&15 source-pre-swizzle; sqi-deferred epilogue; packed labels;
// deterministic fixed-point finalize.

#define BB 8192
#define DD 128
#define MARGIN 0.2f
#define EPS 1e-12f

#define COLS_PER_BLOCK 512
#define ROWS_PER_BLOCK 128                     // 8 waves x 16 rows
#define STAGE_COLS 32
#define NSTAGES 16                             // COLS_PER_BLOCK / STAGE_COLS
#define STAGE_SHORTS (STAGE_COLS * DD)         // 4096 shorts = 8 KB

typedef __attribute__((ext_vector_type(8))) short short8;
typedef __attribute__((ext_vector_type(4))) float f32x4;

__device__ inline unsigned short f2bf(float f) {
    __hip_bfloat16 h = __float2bfloat16(f);
    unsigned short u;
    __builtin_memcpy(&u, &h, 2);
    return u;
}

// ---- prep: bf16 copy + packed {sq,label} meta + init reduction state -------
__global__ __launch_bounds__(256) void prep_kernel(
    const float* __restrict__ x, const int* __restrict__ lab,
    unsigned short* __restrict__ xb, float2* __restrict__ meta,
    unsigned* __restrict__ hp2, unsigned* __restrict__ mn2,
    unsigned long long* __restrict__ fsum, unsigned* __restrict__ fdone) {
    int t = blockIdx.x * blockDim.x + threadIdx.x;   // 0 .. 8192*32-1
    int row = t >> 5;                                 // 32 threads per row
    const float4 v = reinterpret_cast<const float4*>(x)[t];

    union { unsigned short u[4]; uint2 w; } p;
    p.u[0] = f2bf(v.x); p.u[1] = f2bf(v.y);
    p.u[2] = f2bf(v.z); p.u[3] = f2bf(v.w);
    reinterpret_cast<uint2*>(xb)[t] = p.w;

    float s = v.x * v.x + v.y * v.y + v.z * v.z + v.w * v.w;
    #pragma unroll
    for (int m = 16; m >= 1; m >>= 1) s += __shfl_xor(s, m, 64);  // within 32-lane row group
    if ((t & 31) == 0) meta[row] = make_float2(s, __int_as_float(lab[row]));

    if (t < BB) { hp2[t] = 0u; mn2[t] = 0x7f800000u; }  // 0, +inf
    if (t == 0) { *fsum = 0ull; *fdone = 0u; }
}

// ---- main ------------------------------------------------------------------
// 1024 blocks (1D, XCD-swizzled), 512 threads = 8 waves x 16 rows = 128 rows
// x 512-col chunk. 32-col B stages in a 4-buffer ring; vmcnt(2) keeps TWO
// stages in flight across raw barriers.
__global__ __launch_bounds__(512) void triplet_main(
    const unsigned short* __restrict__ xb, const float2* __restrict__ meta,
    unsigned* __restrict__ hp2, unsigned* __restrict__ mn2) {
    const int tid  = threadIdx.x;
    const int wave = tid >> 6;
    const int lane = tid & 63;
    const int l15  = lane & 15;
    const int lhi  = lane >> 4;

    // bijective XCD swizzle (1024 % 8 == 0): each XCD gets a contiguous slab
    // of logical ids -> all 64 row-blocks of 2 column chunks per XCD.
    const int bid = (int)blockIdx.x;
    const int swz = (bid & 7) * 128 + (bid >> 3);
    const int cc  = swz >> 6;                        // column chunk 0..15
    const int rb  = swz & 63;                        // row block    0..63
    const int rbase = rb * ROWS_PER_BLOCK + wave * 16;
    const int cbase = cc * COLS_PER_BLOCK;

    __shared__ unsigned short sb[4][STAGE_SHORTS];   // 4 x 8 KB
    __shared__ float2 smeta[COLS_PER_BLOCK];         // 4 KB

    // A fragments: 16 rows, K=128 in 4 slices (held whole kernel).
    // mfma_f32_16x16x32_bf16 A layout: row = lane&15, k = (lane>>4)*8 + i.
    short8 a[4];
    {
        const unsigned short* ar = xb + (size_t)(rbase + l15) * DD + lhi * 8;
        #pragma unroll
        for (int s = 0; s < 4; ++s)
            a[s] = *reinterpret_cast<const short8*>(ar + s * 32);
    }

    // C/D layout: col = lane&15, row_local = (lane>>4)*4 + r.
    // Row labels packed 4/uint (labels < 64): byte r = label of row lhi*4+r.
    unsigned liw = 0;
    {
        #pragma unroll
        for (int k = 0; k < 4; ++k)
            liw |= ((unsigned)__float_as_int(meta[rbase + lhi * 4 + k].y) & 255u) << (8 * k);
    }
    float hp[4], mn[4];
    #pragma unroll
    for (int r = 0; r < 4; ++r) { hp[r] = -__builtin_inff(); mn[r] = __builtin_inff(); }

    // Stage 32 cols (8 KB) into sb[buf]: 1 x 16B gload_lds per thread.
    // LDS dest linear (wave-uniform base + lane*16); global SOURCE pre-swizzled:
    // LDS(col, b) = G(col, b ^ ((col&15)<<4)).
    auto stage = [&](int g, int buf) {
        const char* src_base = (const char*)(xb + (size_t)(cbase + g * STAGE_COLS) * DD);
        const int o   = tid * 16;                       // 0..8191
        const int row = o >> 8;                         // col index 0..31
        const int byt = (o & 255) ^ ((row & 15) << 4);
        const char* src = src_base + row * 256 + byt;
        char* dst = (char*)&sb[buf][0] + wave * 1024;
        __builtin_amdgcn_global_load_lds(
            (const __attribute__((address_space(1))) void*)src,
            (__attribute__((address_space(3))) void*)dst, 16, 0, 0);
    };

    auto compute_group = [&](int st, int gg, const char* base) {
        const int jl = gg * 16 + l15;                   // col within stage (0..31)
        const int rowoff = jl * 256;
        const int swzb = (jl & 15) << 4;
        short8 b[4];
        #pragma unroll
        for (int s = 0; s < 4; ++s)
            b[s] = *reinterpret_cast<const short8*>(
                base + rowoff + ((s * 64 + lhi * 16) ^ swzb));
        f32x4 acc = {};
        #pragma unroll
        for (int s = 0; s < 4; ++s)
            acc = __builtin_amdgcn_mfma_f32_16x16x32_bf16(a[s], b[s], acc, 0, 0, 0);

        const float2 mj = smeta[st * STAGE_COLS + jl];
        const float sqj = mj.x;
        const int   labj = __float_as_int(mj.y) & 255;
        #pragma unroll
        for (int r = 0; r < 4; ++r) {
            const float d2p = fmaf(acc[r], -2.0f, sqj);  // sqj - 2 dot (sqi deferred)
            const bool eq = (int)((liw >> (8 * r)) & 255u) == labj;
            // self-pair folds into hp: d2' ~ -sqi -> ~0 after +sqi, never wins.
            hp[r] = fmaxf(hp[r], eq ? d2p : -__builtin_inff());
            mn[r] = fminf(mn[r], eq ? __builtin_inff() : d2p);
        }
    };

    // Prologue: smeta (2 dup gload_lds per wave, identical bytes, benign race,
    // keeps per-wave vmcnt counts uniform), then stages 0,1,2.
    {
        const char* msrc = (const char*)(meta + cbase);
        #pragma unroll
        for (int p = 0; p < 4; ++p)
            __builtin_amdgcn_global_load_lds(
                (const __attribute__((address_space(1))) void*)(msrc + p * 1024 + lane * 16),
                (__attribute__((address_space(3))) void*)((char*)smeta + p * 1024), 16, 0, 0);
    }
    stage(0, 0);
    stage(1, 1);
    stage(2, 2);

    // 4-buffer ring: at top of iter st, outstanding (FIFO) = {st, st+1, st+2}
    // (+4 smeta at st=0, drained by the same wait). vmcnt(2) -> stage st
    // landed, st+1/st+2 in flight across the RAW barrier. lgkmcnt(0) -> this
    // wave's reads of buf (st+3)%4 (from iter st-1) are done before overwrite.
    #pragma unroll
    for (int st = 0; st < NSTAGES; ++st) {
        if (st < NSTAGES - 2)
            asm volatile("s_waitcnt lgkmcnt(0) vmcnt(2)" ::: "memory");
        else if (st == NSTAGES - 2)
            asm volatile("s_waitcnt lgkmcnt(0) vmcnt(1)" ::: "memory");
        else
            asm volatile("s_waitcnt lgkmcnt(0) vmcnt(0)" ::: "memory");
        __builtin_amdgcn_s_barrier();
        __builtin_amdgcn_sched_barrier(0);
        if (st + 3 < NSTAGES) stage(st + 3, (st + 3) & 3);
        const char* base = (const char*)&sb[st & 3][0];
        compute_group(st, 0, base);
        __builtin_amdgcn_sched_barrier(0);   // keep live sets (and VGPRs) small
        compute_group(st, 1, base);
    }

    // Epilogue: add deferred sqi; clamp hp >= 0 (exact: ref max(d*posmask)>=0);
    // reduce across the 16 col-lanes; one atomic pair per row.
    #pragma unroll
    for (int r = 0; r < 4; ++r) {
        const float sqi = meta[rbase + lhi * 4 + r].x;
        hp[r] = fmaxf(sqi + hp[r], 0.0f);   // -inf (none seen) -> 0
        mn[r] = sqi + mn[r];                // +inf stays +inf
    }
    #pragma unroll
    for (int m = 1; m < 16; m <<= 1) {
        #pragma unroll
        for (int r = 0; r < 4; ++r) {
            hp[r] = fmaxf(hp[r], __shfl_xor(hp[r], m, 64));
            mn[r] = fminf(mn[r], __shfl_xor(mn[r], m, 64));
        }
    }
    if (l15 == 0) {   // lanes 0,16,32,48 hold the four lhi row-groups
        #pragma unroll
        for (int r = 0; r < 4; ++r) {
            const int i = rbase + lhi * 4 + r;
            atomicMax(&hp2[i], __float_as_uint(hp[r]));  // >=0: uint order == float order
            atomicMin(&mn2[i], __float_as_uint(mn[r]));  // >=0 or +inf
        }
    }
}

// ---- finalize: per-row loss + deterministic fixed-point mean ---------------
// hardest_negative = min_neq d (every row has negatives: 64 labels / 8192).
__device__ inline float d_of(float d2) {
    return (d2 > EPS) ? sqrtf(d2) : 0.0f;
}

__global__ __launch_bounds__(1024) void finalize_kernel(
    const unsigned* __restrict__ hp2, const unsigned* __restrict__ mn2,
    unsigned long long* __restrict__ fsum, unsigned* __restrict__ fdone,
    float* __restrict__ out) {
    const int i = blockIdx.x * 1024 + threadIdx.x;   // 8 blocks x 1024 rows
    const float hpv = d_of(__uint_as_float(hp2[i]));
    const float mnv = d_of(__uint_as_float(mn2[i]));
    float acc = fmaxf(hpv - mnv + MARGIN, 0.0f);

    #pragma unroll
    for (int m = 1; m < 64; m <<= 1) acc += __shfl_xor(acc, m, 64);
    __shared__ float ws[16];
    const int wave = threadIdx.x >> 6;
    if ((threadIdx.x & 63) == 0) ws[wave] = acc;
    __syncthreads();
    if (threadIdx.x == 0) {
        float s = 0.0f;
        #pragma unroll
        for (int w = 0; w < 16; ++w) s += ws[w];
        // deterministic: integer atomic adds are order-independent
        atomicAdd(fsum, (unsigned long long)((double)s * 4294967296.0));
        __threadfence();
        const unsigned old = atomicAdd(fdone, 1u);
        if (old == gridDim.x - 1) {
            const unsigned long long total = atomicAdd(fsum, 0ull);
            out[0] = (float)((double)total / 4294967296.0 / (double)BB);
        }
    }
}

extern "C" void kernel_launch(void* const* d_in, const int* in_sizes, int n_in,
                              void* d_out, int out_size, void* d_ws, size_t ws_size,
                              hipStream_t stream) {
    const float* x = (const float*)d_in[0];
    const int* lab = (const int*)d_in[1];
    float* out = (float*)d_out;

    char* ws = (char*)d_ws;
    unsigned short* xb = (unsigned short*)ws;                          // 2 MB
    float2* meta = (float2*)(ws + (size_t)BB * DD * 2);                // 64 KB
    unsigned* hp2 = (unsigned*)(ws + (size_t)BB * DD * 2 + BB * 8);
    unsigned* mn2 = (unsigned*)(ws + (size_t)BB * DD * 2 + BB * 12);
    unsigned long long* fsum = (unsigned long long*)(ws + (size_t)BB * DD * 2 + BB * 16);
    unsigned* fdone = (unsigned*)(ws + (size_t)BB * DD * 2 + BB * 16 + 8);

    prep_kernel<<<(BB * DD / 4) / 256, 256, 0, stream>>>(x, lab, xb, meta, hp2, mn2, fsum, fdone);
    triplet_main<<<1024, 512, 0, stream>>>(xb, meta, hp2, mn2);
    finalize_kernel<<<BB / 1024, 1024, 0, stream>>>(hp2, mn2, fsum, fdone, out);
}